// Round 3
// baseline (460.201 us; speedup 1.0000x reference)
//
#include <hip/hip_runtime.h>
#include <stdint.h>

#define N_NODES 100000

// ---------------------------------------------------------------- CSR build
__global__ void zero_u32(uint32_t* p, int n){
    int i = blockIdx.x * 256 + threadIdx.x;
    if (i < n) p[i] = 0u;
}

__global__ void count_dst(const int* __restrict__ dst, uint32_t* __restrict__ cnt, int E){
    int e = blockIdx.x * 256 + threadIdx.x;
    if (e < E) atomicAdd((unsigned int*)&cnt[dst[e]], 1u);
}

// block-level scan over 1024 elements (Hillis-Steele in LDS).
__global__ void scan_blocks(const uint32_t* __restrict__ in, uint32_t* __restrict__ out,
                            uint32_t* __restrict__ bsum, int n){
    __shared__ uint32_t tmp[1024];
    int base = blockIdx.x * 1024;
    for (int j = threadIdx.x; j < 1024; j += 256)
        tmp[j] = (base + j < n) ? in[base + j] : 0u;
    __syncthreads();
    for (int off = 1; off < 1024; off <<= 1){
        uint32_t v[4];
        for (int j = 0; j < 4; j++){
            int i = threadIdx.x + j * 256;
            v[j] = (i >= off) ? tmp[i - off] : 0u;
        }
        __syncthreads();
        for (int j = 0; j < 4; j++){
            int i = threadIdx.x + j * 256;
            tmp[i] += v[j];
        }
        __syncthreads();
    }
    for (int j = threadIdx.x; j < 1024; j += 256)
        if (base + j < n) out[base + j] = (j > 0) ? tmp[j - 1] : 0u;
    if (threadIdx.x == 0) bsum[blockIdx.x] = tmp[1023];
}

__global__ void add_boff(uint32_t* __restrict__ out, const uint32_t* __restrict__ boff, int n){
    int base = blockIdx.x * 1024;
    uint32_t add = boff[blockIdx.x];
    for (int j = threadIdx.x; j < 1024; j += 256)
        if (base + j < n) out[base + j] += add;
}

__global__ void fill_csr(const int* __restrict__ src, const int* __restrict__ dst,
                         const uint32_t* __restrict__ off, uint32_t* __restrict__ cur,
                         uint32_t* __restrict__ slot, int E){
    int e = blockIdx.x * 256 + threadIdx.x;
    if (e < E){
        int d = dst[e];
        uint32_t p = atomicAdd((unsigned int*)&cur[d], 1u);
        slot[off[d] + p] = (uint32_t)src[e];
    }
}

__global__ void compute_dinv(const uint32_t* __restrict__ cnt, float* __restrict__ dinv, int n){
    int i = blockIdx.x * 256 + threadIdx.x;
    if (i < n) dinv[i] = rsqrtf((float)(cnt[i] + 1u));   // +1 self-loop; always > 0
}

// ---------------------------------------------------------------- fused layer 1
// out = relu( (A_hat x) @ W1 + b1 ), 32 nodes/block, 256 threads.
// Phase 1: each wave aggregates 8 nodes (pull CSR), writes transposed tile
//          xT[k][r] (k = feature, r = local row, stride 32).
// Phase 2: 4x4 register-blocked GEMM from LDS; W1 staged in two 64-row K-halves
//          so total LDS = 32 KiB + 16 KiB = 48 KiB.
__global__ __launch_bounds__(256) void fused_layer1(const float* __restrict__ X,
        const uint32_t* __restrict__ offs, const uint32_t* __restrict__ cnt,
        const uint32_t* __restrict__ slot, const float* __restrict__ dinv,
        const float* __restrict__ W, const float* __restrict__ bias,
        float* __restrict__ OUT){
    __shared__ float Wl[64 * 128];    // 32 KiB (one K-half of W)
    __shared__ float xT[128 * 32];    // 16 KiB, [k][r]
    int tid = threadIdx.x;
    int r0 = blockIdx.x * 32;

    const float4* W4 = (const float4*)W;    // W is [128][128] row-major -> 32 float4/row
    float4* Wl4 = (float4*)Wl;

    // stage W rows 0..63
    for (int j = tid; j < 2048; j += 256) Wl4[j] = W4[j];

    // phase 1: aggregation. wave wid handles local rows wid*8 .. wid*8+7
    {
        int wid = tid >> 6, lane = tid & 63;
        const float2* X2 = (const float2*)X;
        for (int i = 0; i < 8; i++){
            int r = wid * 8 + i;
            int g = r0 + r;
            uint32_t o = offs[g], c = cnt[g];
            float2 acc = {0.f, 0.f};
            for (uint32_t e = 0; e < c; e++){
                uint32_t s = slot[o + e];
                float ds = dinv[s];
                float2 v = X2[(size_t)s * 64 + lane];
                acc.x += ds * v.x;
                acc.y += ds * v.y;
            }
            float dd = dinv[g];
            float2 self = X2[(size_t)g * 64 + lane];
            xT[(2 * lane + 0) * 32 + r] = dd * (acc.x + dd * self.x);
            xT[(2 * lane + 1) * 32 + r] = dd * (acc.y + dd * self.y);
        }
    }
    __syncthreads();

    // phase 2: [32,128] @ [128,128] with bias + relu
    int cg = tid & 31, rg = tid >> 5;
    float4 acc0 = {0,0,0,0}, acc1 = {0,0,0,0}, acc2 = {0,0,0,0}, acc3 = {0,0,0,0};
    const float4* xT4 = (const float4*)xT;
    #pragma unroll 8
    for (int k = 0; k < 64; k++){
        float4 w  = Wl4[k * 32 + cg];
        float4 xv = xT4[k * 8 + rg];   // rows rg*4 .. rg*4+3 at feature k
        acc0.x += xv.x * w.x; acc0.y += xv.x * w.y; acc0.z += xv.x * w.z; acc0.w += xv.x * w.w;
        acc1.x += xv.y * w.x; acc1.y += xv.y * w.y; acc1.z += xv.y * w.z; acc1.w += xv.y * w.w;
        acc2.x += xv.z * w.x; acc2.y += xv.z * w.y; acc2.z += xv.z * w.z; acc2.w += xv.z * w.w;
        acc3.x += xv.w * w.x; acc3.y += xv.w * w.y; acc3.z += xv.w * w.z; acc3.w += xv.w * w.w;
    }
    __syncthreads();
    // stage W rows 64..127
    for (int j = tid; j < 2048; j += 256) Wl4[j] = W4[2048 + j];
    __syncthreads();
    #pragma unroll 8
    for (int k = 0; k < 64; k++){
        float4 w  = Wl4[k * 32 + cg];
        float4 xv = xT4[(64 + k) * 8 + rg];
        acc0.x += xv.x * w.x; acc0.y += xv.x * w.y; acc0.z += xv.x * w.z; acc0.w += xv.x * w.w;
        acc1.x += xv.y * w.x; acc1.y += xv.y * w.y; acc1.z += xv.y * w.z; acc1.w += xv.y * w.w;
        acc2.x += xv.z * w.x; acc2.y += xv.z * w.y; acc2.z += xv.z * w.z; acc2.w += xv.z * w.w;
        acc3.x += xv.w * w.x; acc3.y += xv.w * w.y; acc3.z += xv.w * w.z; acc3.w += xv.w * w.w;
    }

    float4 b = ((const float4*)bias)[cg];
    float4* O4 = (float4*)OUT;
    int rowbase = r0 + rg * 4;
    float4 o0 = {fmaxf(acc0.x + b.x, 0.f), fmaxf(acc0.y + b.y, 0.f), fmaxf(acc0.z + b.z, 0.f), fmaxf(acc0.w + b.w, 0.f)};
    float4 o1 = {fmaxf(acc1.x + b.x, 0.f), fmaxf(acc1.y + b.y, 0.f), fmaxf(acc1.z + b.z, 0.f), fmaxf(acc1.w + b.w, 0.f)};
    float4 o2 = {fmaxf(acc2.x + b.x, 0.f), fmaxf(acc2.y + b.y, 0.f), fmaxf(acc2.z + b.z, 0.f), fmaxf(acc2.w + b.w, 0.f)};
    float4 o3 = {fmaxf(acc3.x + b.x, 0.f), fmaxf(acc3.y + b.y, 0.f), fmaxf(acc3.z + b.z, 0.f), fmaxf(acc3.w + b.w, 0.f)};
    O4[(size_t)(rowbase + 0) * 32 + cg] = o0;
    O4[(size_t)(rowbase + 1) * 32 + cg] = o1;
    O4[(size_t)(rowbase + 2) * 32 + cg] = o2;
    O4[(size_t)(rowbase + 3) * 32 + cg] = o3;
}

// ---------------------------------------------------------------- fused layer 2
// out = (A_hat h1) @ W2 + b2, 32 nodes/block, 256 threads. LDS = 20 + 16 = 36 KiB.
__global__ __launch_bounds__(256) void fused_layer2(const float* __restrict__ H,
        const uint32_t* __restrict__ offs, const uint32_t* __restrict__ cnt,
        const uint32_t* __restrict__ slot, const float* __restrict__ dinv,
        const float* __restrict__ W, const float* __restrict__ bias,
        float* __restrict__ OUT){
    __shared__ float Wl[128 * 40];    // 20 KiB
    __shared__ float xT[128 * 32];    // 16 KiB, [k][r]
    int tid = threadIdx.x;
    int r0 = blockIdx.x * 32;

    const float4* W4 = (const float4*)W;
    float4* Wl4 = (float4*)Wl;
    for (int j = tid; j < 1280; j += 256) Wl4[j] = W4[j];

    // phase 1: aggregation of H rows
    {
        int wid = tid >> 6, lane = tid & 63;
        const float2* H2 = (const float2*)H;
        for (int i = 0; i < 8; i++){
            int r = wid * 8 + i;
            int g = r0 + r;
            uint32_t o = offs[g], c = cnt[g];
            float2 acc = {0.f, 0.f};
            for (uint32_t e = 0; e < c; e++){
                uint32_t s = slot[o + e];
                float ds = dinv[s];
                float2 v = H2[(size_t)s * 64 + lane];
                acc.x += ds * v.x;
                acc.y += ds * v.y;
            }
            float dd = dinv[g];
            float2 self = H2[(size_t)g * 64 + lane];
            xT[(2 * lane + 0) * 32 + r] = dd * (acc.x + dd * self.x);
            xT[(2 * lane + 1) * 32 + r] = dd * (acc.y + dd * self.y);
        }
    }
    __syncthreads();

    // phase 2: [32,128] @ [128,40] + bias. thread = (row r = tid>>3, colgroup cw = tid&7)
    int r = tid >> 3, cw = tid & 7;
    float acc[5] = {0.f, 0.f, 0.f, 0.f, 0.f};
    #pragma unroll 8
    for (int k = 0; k < 128; k++){
        float xv = xT[k * 32 + r];
        #pragma unroll
        for (int j = 0; j < 5; j++)
            acc[j] += xv * Wl[k * 40 + 5 * cw + j];
    }
    int g = r0 + r;
    #pragma unroll
    for (int j = 0; j < 5; j++)
        OUT[(size_t)g * 40 + 5 * cw + j] = acc[j] + bias[5 * cw + j];
}

// ---------------------------------------------------------------- launch
extern "C" void kernel_launch(void* const* d_in, const int* in_sizes, int n_in,
                              void* d_out, int out_size, void* d_ws, size_t ws_size,
                              hipStream_t stream) {
    const float* x   = (const float*)d_in[0];
    const int*   ei  = (const int*)d_in[1];      // int32! harness converts integer inputs
    const float* W1  = (const float*)d_in[2];
    const float* b1  = (const float*)d_in[3];
    const float* W2  = (const float*)d_in[4];
    const float* b2  = (const float*)d_in[5];
    float*       out = (float*)d_out;

    const int N = N_NODES;
    const int E = in_sizes[1] / 2;
    const int* src = ei;
    const int* dst = ei + E;

    // workspace carve-up (512B-aligned). Total ~56 MiB.
    char* ws = (char*)d_ws;
    size_t o = 0;
    auto alloc = [&](size_t bytes) -> char* {
        char* p = ws + o;
        o += (bytes + 511) & ~(size_t)511;
        return p;
    };
    uint32_t* cnt   = (uint32_t*)alloc((size_t)N * 4);
    uint32_t* offs  = (uint32_t*)alloc((size_t)N * 4);
    uint32_t* cur   = (uint32_t*)alloc((size_t)N * 4);
    uint32_t* bsum  = (uint32_t*)alloc(1024 * 4);
    uint32_t* boff  = (uint32_t*)alloc(1024 * 4);
    uint32_t* bsum2 = (uint32_t*)alloc(512);
    uint32_t* slot  = (uint32_t*)alloc((size_t)E * 4);
    float*    dinv  = (float*)alloc((size_t)N * 4);
    float*    A     = (float*)alloc((size_t)N * 128 * 4);   // layer-1 activations

    const int nblk_nodes = (N + 255) / 256;       // 391
    const int nblk_edges = (E + 255) / 256;       // 2500
    const int nblk_scan  = (N + 1023) / 1024;     // 98

    // --- graph structure ---
    zero_u32<<<nblk_nodes, 256, 0, stream>>>(cnt, N);
    zero_u32<<<nblk_nodes, 256, 0, stream>>>(cur, N);
    count_dst<<<nblk_edges, 256, 0, stream>>>(dst, cnt, E);
    scan_blocks<<<nblk_scan, 256, 0, stream>>>(cnt, offs, bsum, N);
    scan_blocks<<<1, 256, 0, stream>>>(bsum, boff, bsum2, nblk_scan);
    add_boff<<<nblk_scan, 256, 0, stream>>>(offs, boff, N);
    fill_csr<<<nblk_edges, 256, 0, stream>>>(src, dst, offs, cur, slot, E);
    compute_dinv<<<nblk_nodes, 256, 0, stream>>>(cnt, dinv, N);

    // --- layer 1: A = relu( (A_hat x) W1 + b1 ) ---
    fused_layer1<<<N / 32, 256, 0, stream>>>(x, offs, cnt, slot, dinv, W1, b1, A);

    // --- layer 2: out = (A_hat A) W2 + b2 ---
    fused_layer2<<<N / 32, 256, 0, stream>>>(A, offs, cnt, slot, dinv, W2, b2, out);
}